// Round 9
// baseline (60.873 us; speedup 1.0000x reference)
//
#include <hip/hip_runtime.h>

#define NBATCH 2048
#define NCONF  256
#define NMO    40
#define NELEC  16
#define SSTRIDE 20             // padded column stride (floats): 80 B, 16B-aligned
#define GROWTH_LIMIT 16384.0f  // max |multiplier| before pivoted redo

typedef float v2f __attribute__((ext_vector_type(2)));

// Rows packed as 4x float2 -> elimination row-updates become v_pk_fma_f32
// (VOP3P packed 2xf32). Hot path ~180 issue slots/det.

// ---- hot path: no-pivot LU, growth-monitored ----
__device__ __forceinline__ float det8_nopivot(v2f a[8][4], float& mf) {
    float det = 1.0f;
    mf = 0.0f;
    #pragma unroll
    for (int k = 0; k < 8; ++k) {
        const float piv = a[k][k >> 1][k & 1];
        det *= piv;
        const float inv = __builtin_amdgcn_rcpf(piv);
        #pragma unroll
        for (int i = k + 1; i < 8; ++i) {
            const float f = a[i][k >> 1][k & 1] * inv;
            mf = fmaxf(mf, fabsf(f));
            const v2f nf = { -f, -f };
            #pragma unroll
            for (int jj = (k + 1) >> 1; jj < 4; ++jj) {
                a[i][jj] = __builtin_elementwise_fma(nf, a[k][jj], a[i][jj]);
            }
        }
    }
    return det;
}

// ---- cold path: partial-pivot LU (exec-masked, ~6% of waves) ----
__device__ __forceinline__ float det8_pivoted(v2f a[8][4]) {
    float det = 1.0f;
    #pragma unroll
    for (int k = 0; k < 8; ++k) {
        #pragma unroll
        for (int i = k + 1; i < 8; ++i) {
            const bool sw = fabsf(a[i][k >> 1][k & 1]) > fabsf(a[k][k >> 1][k & 1]);
            #pragma unroll
            for (int jj = k >> 1; jj < 4; ++jj) {
                const v2f tk = a[k][jj];
                const v2f ti = a[i][jj];
                a[k][jj] = sw ? ti : tk;
                a[i][jj] = sw ? tk : ti;
            }
            det = sw ? -det : det;
        }
        const float piv = a[k][k >> 1][k & 1];
        det *= piv;
        const float inv = __builtin_amdgcn_rcpf(piv);
        #pragma unroll
        for (int i = k + 1; i < 8; ++i) {
            const float f = a[i][k >> 1][k & 1] * inv;
            const v2f nf = { -f, -f };
            #pragma unroll
            for (int jj = (k + 1) >> 1; jj < 4; ++jj) {
                a[i][jj] = __builtin_elementwise_fma(nf, a[k][jj], a[i][jj]);
            }
        }
    }
    return det;
}

__device__ __forceinline__ void gather8(const float* __restrict__ smoT,
                                        const int idx[8], int ebase,
                                        v2f a[8][4]) {
    #pragma unroll
    for (int j = 0; j < 8; ++j) {
        const float4* col = (const float4*)&smoT[idx[j] * SSTRIDE + ebase];
        const float4 lo = col[0];
        const float4 hi = col[1];
        const int jj = j >> 1, jl = j & 1;
        a[0][jj][jl] = lo.x; a[1][jj][jl] = lo.y;
        a[2][jj][jl] = lo.z; a[3][jj][jl] = lo.w;
        a[4][jj][jl] = hi.x; a[5][jj][jl] = hi.y;
        a[6][jj][jl] = hi.z; a[7][jj][jl] = hi.w;
    }
}

// One det per thread; thread pairs (2c,2c+1) = config c's up/down dets.
// __launch_bounds__(256,6): target <=~85 VGPR -> 6 waves/SIMD resident
// (was 4 at the 128-VGPR cap). The LU dep chain (~200 cyc/det, serial
// across k) needs the extra residency; issue slots are only ~360 cyc/wave.
// True register need ~76-90 (R5's standalone pivoted kernel: 76 VGPR).
__global__ __launch_bounds__(256, 6) void slater_pool_kernel(
    const float* __restrict__ mo,     // (NBATCH, NELEC, NMO)
    const int*   __restrict__ cup,    // (NCONF, 8)
    const int*   __restrict__ cdown,  // (NCONF, 8)
    float*       __restrict__ out)    // (NBATCH, NCONF)
{
    __shared__ __align__(16) float smoT[NMO * SSTRIDE];  // 3200 B

    const int b    = blockIdx.x >> 1;
    const int half = blockIdx.x & 1;
    const int tid  = threadIdx.x;

    // Stage mo[b] transposed: smoT[m*SSTRIDE + e] = mo[b,e,m].
    if (tid < NELEC * NMO / 4) {
        const float4 v = ((const float4*)(mo + b * (NELEC * NMO)))[tid];
        const int e = (tid * 4) / NMO;
        const int m = (tid * 4) - e * NMO;
        smoT[(m + 0) * SSTRIDE + e] = v.x;
        smoT[(m + 1) * SSTRIDE + e] = v.y;
        smoT[(m + 2) * SSTRIDE + e] = v.z;
        smoT[(m + 3) * SSTRIDE + e] = v.w;
    }
    __syncthreads();

    const int c    = half * 128 + (tid >> 1);  // config 0..255
    const int spin = tid & 1;                  // 0 = up, 1 = down

    const int* cfg = spin ? cdown : cup;
    const int4 i0 = ((const int4*)cfg)[c * 2 + 0];
    const int4 i1 = ((const int4*)cfg)[c * 2 + 1];
    const int idx[8] = {i0.x, i0.y, i0.z, i0.w, i1.x, i1.y, i1.z, i1.w};
    const int ebase = spin << 3;

    v2f a[8][4];
    gather8(smoT, idx, ebase, a);

    float mf;
    float det = det8_nopivot(a, mf);

    // Rare redo: growth too large or det inf/NaN (NaN fails both compares).
    if ((!(mf <= GROWTH_LIMIT)) || (!(fabsf(det) < 1e30f))) {
        gather8(smoT, idx, ebase, a);
        det = det8_pivoted(a);
    }

    const float other = __shfl_xor(det, 1);
    if (spin == 0) {
        out[b * NCONF + c] = det * other;
    }
}

extern "C" void kernel_launch(void* const* d_in, const int* in_sizes, int n_in,
                              void* d_out, int out_size, void* d_ws, size_t ws_size,
                              hipStream_t stream) {
    const float* mo    = (const float*)d_in[0];
    const int*   cup   = (const int*)d_in[1];
    const int*   cdown = (const int*)d_in[2];
    float*       out   = (float*)d_out;

    slater_pool_kernel<<<NBATCH * 2, 256, 0, stream>>>(mo, cup, cdown, out);
}

// Round 10
// 14.270 us; speedup vs baseline: 4.2659x; 4.2659x over previous
//
#include <hip/hip_runtime.h>

#define NBATCH 2048
#define NCONF  256
#define NMO    40
#define NELEC  16
#define SSTRIDE 20             // padded column stride (floats): 80 B, 16B-aligned
#define GROWTH_LIMIT 65536.0f  // max |multiplier| before pivoted redo

typedef float v2f __attribute__((ext_vector_type(2)));

// Rows packed as 4x float2 -> elimination row-updates become v_pk_fma_f32.

// ---- hot path: no-pivot LU, growth-monitored (~180 issue slots) ----
__device__ __forceinline__ float det8_nopivot(v2f a[8][4], float& mf) {
    float det = 1.0f;
    mf = 0.0f;
    #pragma unroll
    for (int k = 0; k < 8; ++k) {
        const float piv = a[k][k >> 1][k & 1];
        det *= piv;
        const float inv = __builtin_amdgcn_rcpf(piv);
        #pragma unroll
        for (int i = k + 1; i < 8; ++i) {
            const float f = a[i][k >> 1][k & 1] * inv;
            mf = fmaxf(mf, fabsf(f));
            const v2f nf = { -f, -f };
            #pragma unroll
            for (int jj = (k + 1) >> 1; jj < 4; ++jj) {
                a[i][jj] = __builtin_elementwise_fma(nf, a[k][jj], a[i][jj]);
            }
        }
    }
    return det;
}

// ---- cold path: partial-pivot LU (exec-masked, ~1.5% of waves) ----
__device__ __forceinline__ float det8_pivoted(v2f a[8][4]) {
    float det = 1.0f;
    #pragma unroll
    for (int k = 0; k < 8; ++k) {
        #pragma unroll
        for (int i = k + 1; i < 8; ++i) {
            const bool sw = fabsf(a[i][k >> 1][k & 1]) > fabsf(a[k][k >> 1][k & 1]);
            #pragma unroll
            for (int jj = k >> 1; jj < 4; ++jj) {
                const v2f tk = a[k][jj];
                const v2f ti = a[i][jj];
                a[k][jj] = sw ? ti : tk;
                a[i][jj] = sw ? tk : ti;
            }
            det = sw ? -det : det;
        }
        const float piv = a[k][k >> 1][k & 1];
        det *= piv;
        const float inv = __builtin_amdgcn_rcpf(piv);
        #pragma unroll
        for (int i = k + 1; i < 8; ++i) {
            const float f = a[i][k >> 1][k & 1] * inv;
            const v2f nf = { -f, -f };
            #pragma unroll
            for (int jj = (k + 1) >> 1; jj < 4; ++jj) {
                a[i][jj] = __builtin_elementwise_fma(nf, a[k][jj], a[i][jj]);
            }
        }
    }
    return det;
}

__device__ __forceinline__ void gather8(const float* __restrict__ smoT,
                                        const int idx[8], int ebase,
                                        v2f a[8][4]) {
    #pragma unroll
    for (int j = 0; j < 8; ++j) {
        const float4* col = (const float4*)&smoT[idx[j] * SSTRIDE + ebase];
        const float4 lo = col[0];
        const float4 hi = col[1];
        const int jj = j >> 1, jl = j & 1;
        a[0][jj][jl] = lo.x; a[1][jj][jl] = lo.y;
        a[2][jj][jl] = lo.z; a[3][jj][jl] = lo.w;
        a[4][jj][jl] = hi.x; a[5][jj][jl] = hi.y;
        a[6][jj][jl] = hi.z; a[7][jj][jl] = hi.w;
    }
}

// One det per thread; thread pairs (2c,2c+1) = config c's up/down dets.
// __launch_bounds__(256,4): cap 128 VGPR, 4 waves/SIMD. Proven in R9 that the
// kernel CANNOT fit 85 VGPR (6 waves) -> allocator collapses to 40+spills.
__global__ __launch_bounds__(256, 4) void slater_pool_kernel(
    const float* __restrict__ mo,     // (NBATCH, NELEC, NMO)
    const int*   __restrict__ cup,    // (NCONF, 8)
    const int*   __restrict__ cdown,  // (NCONF, 8)
    float*       __restrict__ out)    // (NBATCH, NCONF)
{
    __shared__ __align__(16) float smoT[NMO * SSTRIDE];  // 3200 B

    const int b    = blockIdx.x >> 1;
    const int half = blockIdx.x & 1;
    const int tid  = threadIdx.x;

    const int c    = half * 128 + (tid >> 1);  // config 0..255
    const int spin = tid & 1;                  // 0 = up, 1 = down

    // Hoisted config loads: L2 latency overlaps the staging wait below
    // (these sit above __syncthreads so they never serialize after it).
    const int* cfg = spin ? cdown : cup;
    const int4 i0 = ((const int4*)cfg)[c * 2 + 0];
    const int4 i1 = ((const int4*)cfg)[c * 2 + 1];
    const int idx[8] = {i0.x, i0.y, i0.z, i0.w, i1.x, i1.y, i1.z, i1.w};
    const int ebase = spin << 3;

    // Stage mo[b] transposed: smoT[m*SSTRIDE + e] = mo[b,e,m].
    if (tid < NELEC * NMO / 4) {
        const float4 v = ((const float4*)(mo + b * (NELEC * NMO)))[tid];
        const int e = (tid * 4) / NMO;
        const int m = (tid * 4) - e * NMO;
        smoT[(m + 0) * SSTRIDE + e] = v.x;
        smoT[(m + 1) * SSTRIDE + e] = v.y;
        smoT[(m + 2) * SSTRIDE + e] = v.z;
        smoT[(m + 3) * SSTRIDE + e] = v.w;
    }
    __syncthreads();

    v2f a[8][4];
    gather8(smoT, idx, ebase, a);

    float mf;
    float det = det8_nopivot(a, mf);

    // Rare redo: growth too large or det inf/NaN (NaN fails both compares).
    if ((!(mf <= GROWTH_LIMIT)) || (!(fabsf(det) < 1e30f))) {
        gather8(smoT, idx, ebase, a);
        det = det8_pivoted(a);
    }

    const float other = __shfl_xor(det, 1);
    if (spin == 0) {
        out[b * NCONF + c] = det * other;
    }
}

extern "C" void kernel_launch(void* const* d_in, const int* in_sizes, int n_in,
                              void* d_out, int out_size, void* d_ws, size_t ws_size,
                              hipStream_t stream) {
    const float* mo    = (const float*)d_in[0];
    const int*   cup   = (const int*)d_in[1];
    const int*   cdown = (const int*)d_in[2];
    float*       out   = (float*)d_out;

    slater_pool_kernel<<<NBATCH * 2, 256, 0, stream>>>(mo, cup, cdown, out);
}